// Round 2
// baseline (142.881 us; speedup 1.0000x reference)
//
#include <hip/hip_runtime.h>

// Problem constants (match reference setup_inputs)
#define BB     4
#define NN     100000
#define CC     128
#define RESO   128
#define PIX    (RESO * RESO)     // 16384 pixels per (b, plane)
#define NCHUNK 4                 // channel split for K1 parallelism
#define CHUNK  (CC / NCHUNK)     // 32 channels per chunk

// ws layout: ws[plane*4+b][pix][NCHUNK]  (float) -> 12 * 16384 * 4 * 4B = 3 MB
// K2 reads one pixel's 4 chunk-partials as an aligned float4.

// ---------------------------------------------------------------------------
// Kernel 1: partial channel reduction with fc_w, float4-vectorized over pixels.
// grid = (16 tiles, 12 = plane*4+b, 4 chunks), block = 256  -> 768 blocks (3/CU)
// Each thread: one float4 pixel-column, 32 channels -> 32 float4 loads (16B/lane).
// ---------------------------------------------------------------------------
__global__ __launch_bounds__(256) void reduce_planes_k(
    const float* __restrict__ cxz, const float* __restrict__ cxy,
    const float* __restrict__ cyz, const float* __restrict__ fcw,
    float* __restrict__ ws)
{
    __shared__ float w[CHUNK];
    const int t     = threadIdx.x;
    const int tile  = blockIdx.x;    // 0..15
    const int pb    = blockIdx.y;    // 0..11  (plane*4 + b)
    const int chunk = blockIdx.z;    // 0..3
    const int plane = pb >> 2;
    const int b     = pb & 3;

    if (t < CHUNK) w[t] = fcw[chunk * CHUNK + t];
    __syncthreads();

    const float* __restrict__ img = (plane == 0) ? cxz : (plane == 1) ? cxy : cyz;

    const int col = tile * 256 + t;                       // float4 column, 0..4095
    const float4* __restrict__ base =
        (const float4*)(img + ((size_t)b * CC + chunk * CHUNK) * PIX) + col;

    float4 acc = {0.f, 0.f, 0.f, 0.f};
#pragma unroll 8
    for (int c = 0; c < CHUNK; ++c) {
        float4 v = base[(size_t)c * (PIX / 4)];
        float wc = w[c];
        acc.x = fmaf(wc, v.x, acc.x);
        acc.y = fmaf(wc, v.y, acc.y);
        acc.z = fmaf(wc, v.z, acc.z);
        acc.w = fmaf(wc, v.w, acc.w);
    }

    // interleaved store: ws[pb][pixel][chunk]; thread owns pixels 4col..4col+3
    float* __restrict__ o = ws + ((size_t)pb * PIX) * NCHUNK + chunk;
    const int pix0 = col * 4;
    o[(size_t)(pix0 + 0) * NCHUNK] = acc.x;
    o[(size_t)(pix0 + 1) * NCHUNK] = acc.y;
    o[(size_t)(pix0 + 2) * NCHUNK] = acc.z;
    o[(size_t)(pix0 + 3) * NCHUNK] = acc.w;
}

// ---------------------------------------------------------------------------
// Kernel 2: per-point bilinear sample of the reduced planes + linear head.
// Per plane: 4 aligned float4 gathers (taps x0,x1 at rows y0,y1; 4 chunks each).
// ---------------------------------------------------------------------------
__device__ __forceinline__ float hsum4(float4 q) {
    return (q.x + q.y) + (q.z + q.w);
}

__device__ __forceinline__ float bilin(const float4* __restrict__ pb4,
                                       float a, float bcoord)
{
    const float INV = 1.0f / 1.10001f;     // constant-folded reciprocal
    const float HI  = 1.0f - 1e-5f;

    float u = fminf(fmaxf(fmaf(a,      INV, 0.5f), 0.0f), HI);
    float v = fminf(fmaxf(fmaf(bcoord, INV, 0.5f), 0.0f), HI);

    float x = u * 127.0f;                  // in [0, 126.99873] -> x0<=126, x1<=127
    float y = v * 127.0f;
    float xf = floorf(x), yf = floorf(y);
    float wx = x - xf,    wy = y - yf;

    int r0 = (int)yf * RESO + (int)xf;     // no clamps needed (see bounds above)
    int r1 = r0 + RESO;

    float v00 = hsum4(pb4[r0]);
    float v01 = hsum4(pb4[r0 + 1]);
    float v10 = hsum4(pb4[r1]);
    float v11 = hsum4(pb4[r1 + 1]);

    float top = fmaf(wx, v01 - v00, v00);
    float bot = fmaf(wx, v11 - v10, v10);
    return fmaf(wy, bot - top, top);
}

__global__ __launch_bounds__(256) void sample_k(
    const float* __restrict__ p, const float* __restrict__ ws,
    const float* __restrict__ fcw, const float* __restrict__ fcb,
    float* __restrict__ out)
{
    const int i = blockIdx.x * 256 + threadIdx.x;   // over B*N
    if (i >= BB * NN) return;

    const float p0 = p[3 * i + 0];
    const float p1 = p[3 * i + 1];
    const float p2 = p[3 * i + 2];

    const int b = i / NN;
    const float4* __restrict__ w0 = (const float4*)ws + (size_t)(0 * 4 + b) * PIX;
    const float4* __restrict__ w1 = (const float4*)ws + (size_t)(1 * 4 + b) * PIX;
    const float4* __restrict__ w2 = (const float4*)ws + (size_t)(2 * 4 + b) * PIX;

    float s = bilin(w0, p0, p2)    // c_xz: (u=p0, v=p2)
            + bilin(w1, p0, p1)    // c_xy: (u=p0, v=p1)
            + bilin(w2, p1, p2);   // c_yz: (u=p1, v=p2)

    s += p0 * fcw[CC + 0] + p1 * fcw[CC + 1] + p2 * fcw[CC + 2] + fcb[0];

    out[i] = s;
}

// ---------------------------------------------------------------------------
extern "C" void kernel_launch(void* const* d_in, const int* in_sizes, int n_in,
                              void* d_out, int out_size, void* d_ws, size_t ws_size,
                              hipStream_t stream) {
    const float* p   = (const float*)d_in[0];
    const float* cxz = (const float*)d_in[1];
    const float* cxy = (const float*)d_in[2];
    const float* cyz = (const float*)d_in[3];
    const float* fcw = (const float*)d_in[4];
    const float* fcb = (const float*)d_in[5];
    float* out = (float*)d_out;
    float* ws  = (float*)d_ws;   // needs 12 * PIX * 4 floats = 3 MB

    dim3 g1(16, 12, NCHUNK);
    reduce_planes_k<<<g1, 256, 0, stream>>>(cxz, cxy, cyz, fcw, ws);

    const int npts = BB * NN;
    sample_k<<<(npts + 255) / 256, 256, 0, stream>>>(p, ws, fcw, fcb, out);
}